// Round 11
// baseline (206.219 us; speedup 1.0000x reference)
//
#include <hip/hip_runtime.h>
#include <hip/hip_bf16.h>

#define NAQ 35
#define NME 18
#define NN  53
#define FD  64
#define CTXD 60
#define PERB 2          // batch elements per block

// ---- ws layout ----
// u16 [0, 2048): Wt[64][32] bf16  (Wt[n][k] = k<16 ? Wxa[k][n] : Wxm[k-16][n])
#define CVI_F   1024    // float: 8*16 inp-part of folded C-vectors
#define CVE_F   1152    // float: 8*12 emb-part
#define SVC_F   1248    // float: 4*53 ctx-part of projections
#define EBW_F   1460    // float: 53*56 masked bias (1e30 sentinel)
#define WS_FLOATS 4428

// ---- LDS layout (float offsets; u16 regions 16B-aligned) ----
#define L_CVI   0       // 128
#define L_CVE   128     // 96
#define L_SVC   224     // 212
#define L_ETA   436     // 300: staged embedding tables (aqi 158 | meo 142)
#define L_AF    736     // u16[64][40] block-diag A bf16 (1280 f)
#define L_EFA   2016    // 35*9 fp32 emb (aqi)
#define L_EFM   2331    // 18*11 fp32 emb (meo)
#define L_PT    736     // u16[64][72]: P bf16 — ALIASES AF/EFA/EFM (dead); also out-stage
#define L_ATT   3040    // u16[64][72]: attri transposed bf16 (2304 f)
#define L_SVW   5344    // 212
#define S_TOTAL 5556    // 22,224 B -> 7 blocks/CU
#define P_STR   72
#define AF_STR  40

typedef unsigned int   u32;
typedef unsigned short u16;
typedef short s8v __attribute__((ext_vector_type(8)));
typedef float f4v __attribute__((ext_vector_type(4)));

__device__ __forceinline__ float ldf(const void* p, long i, bool bf) {
  if (bf) { u16 h = ((const u16*)p)[i]; return __uint_as_float(((u32)h) << 16); }
  return ((const float*)p)[i];
}
__device__ __forceinline__ u16 f2bf(float f) {
  u32 u = __float_as_uint(f);
  return (u16)((u + 0x7FFFu + ((u >> 16) & 1u)) >> 16);
}
__device__ __forceinline__ bool sniff_bf16(const void* ctx) {
  const u32* w = (const u32*)ctx;
  bool ok = true;
#pragma unroll
  for (int k = 0; k < 32; ++k) {
    u32 e = (w[k] >> 7) & 0xFFu;
    ok = ok && (e >= 96u && e <= 160u);
  }
  return ok;
}
__device__ __forceinline__ s8v ld_frag(const u16* p) {
  union { float4 f; s8v s; } u;
  u.f = *(const float4*)(const void*)p;
  return u.s;
}

// =======================================================================
// prep: batch-invariant tables -> ws  (verified round 9)
// =======================================================================
__global__ void prep_kernel(
    const void* __restrict__ ctx, const void* __restrict__ adjn,
    const void* __restrict__ Wxa, const void* __restrict__ Wxm,
    const void* __restrict__ Wua, const void* __restrict__ Wum,
    const void* __restrict__ a_aa, const void* __restrict__ a_am,
    const void* __restrict__ a_ma, const void* __restrict__ a_mm,
    const int* __restrict__ adj, float* __restrict__ ws)
{
  const bool bf = sniff_bf16(ctx);
  int tid = blockIdx.x * blockDim.x + threadIdx.x;
  if (tid < 2048) {                        // Wt[n][k] bf16
    int n = tid >> 5, kk = tid & 31;
    float v = (kk < 16) ? ldf(Wxa, kk * 64 + n, bf)
                        : ldf(Wxm, (kk - 16) * 64 + n, bf);
    ((u16*)ws)[tid] = f2bf(v);
    return;
  }
  int fi = tid - 1024;                     // float index
  if (fi < CVE_F) {                        // CVi[tr][k], k<16
    int idx = fi - CVI_F;
    int tr = idx >> 4, k = idx & 15;
    const void* Wu = (tr < 4) ? Wua : Wum;
    const void* av; int off;
    switch (tr) {
      case 0: av = a_aa; off = 0;   break;
      case 1: av = a_am; off = 0;   break;
      case 2: av = a_aa; off = 124; break;
      case 3: av = a_ma; off = 124; break;
      case 4: av = a_ma; off = 0;   break;
      case 5: av = a_mm; off = 0;   break;
      case 6: av = a_am; off = 124; break;
      default: av = a_mm; off = 124; break;
    }
    float s = 0.f;
    for (int f = 0; f < 64; ++f) s += ldf(Wu, k * 64 + f, bf) * ldf(av, off + f, bf);
    ws[fi] = s;
  } else if (fi < SVC_F) {                 // CVe[tr][e]
    int idx = fi - CVE_F;
    int tr = idx / 12, e = idx - tr * 12;
    int E = (tr < 4) ? 8 : 10;
    float v = 0.f;
    if (e < E) {
      const void* Wu = (tr < 4) ? Wua : Wum;
      const void* av; int off;
      switch (tr) {
        case 0: av = a_aa; off = 0;   break;
        case 1: av = a_am; off = 0;   break;
        case 2: av = a_aa; off = 124; break;
        case 3: av = a_ma; off = 124; break;
        case 4: av = a_ma; off = 0;   break;
        case 5: av = a_mm; off = 0;   break;
        case 6: av = a_am; off = 124; break;
        default: av = a_mm; off = 124; break;
      }
      float s = 0.f;
      for (int f = 0; f < 64; ++f) s += ldf(Wu, (16 + e) * 64 + f, bf) * ldf(av, off + f, bf);
      v = s;
    }
    ws[fi] = v;
  } else if (fi < EBW_F) {                 // SVC
    int idx = fi - SVC_F;
    int arr = idx / 53, i = idx - arr * 53;
    int isA = (i < NAQ);
    const void* av; int off;
    if (arr == 0)      { av = isA ? a_aa : a_ma; off = 64;  }
    else if (arr == 1) { av = isA ? a_am : a_mm; off = 64;  }
    else if (arr == 2) { av = isA ? a_aa : a_am; off = 188; }
    else               { av = isA ? a_ma : a_mm; off = 188; }
    float s = 0.f;
    for (int c = 0; c < CTXD; ++c) s += ldf(ctx, i * CTXD + c, bf) * ldf(av, off + c, bf);
    ws[fi] = s;
  } else if (fi < WS_FLOATS) {             // EB masked bias
    int idx = fi - EBW_F;
    int i = idx / 56, j = idx - i * 56;
    float v = 1e30f;
    if (j < NN && adj[i * NN + j] > 0) {
      const void* aq = (i < NAQ) ? ((j < NAQ) ? a_aa : a_am)
                                 : ((j < NAQ) ? a_ma : a_mm);
      v = ldf(adjn, i * NN + j, bf) * ldf(aq, 248, bf);
    }
    ws[fi] = v;
  }
}

// =======================================================================
// main: one block = PERB batch elements; both GEMMs on MFMA
// =======================================================================
__global__ __launch_bounds__(256, 7) void hga_main(
    const void* __restrict__ aqi_inp, const void* __restrict__ meo_inp,
    const void* __restrict__ ctx,
    const void* __restrict__ aqi_idE, const void* __restrict__ aqi_monthE,
    const void* __restrict__ aqi_weekdayE, const void* __restrict__ aqi_hourE,
    const void* __restrict__ meo_windE, const void* __restrict__ meo_idE,
    const void* __restrict__ meo_monthE, const void* __restrict__ meo_weekdayE,
    const void* __restrict__ meo_hourE,
    const int* __restrict__ aqi_ex, const int* __restrict__ meo_ex,
    const float* __restrict__ ws, void* __restrict__ out, int B)
{
  __shared__ __align__(16) float sm[S_TOTAL];
  const int t = threadIdx.x;
  const bool bf = sniff_bf16(ctx);
  u16* AFu = (u16*)(sm + L_AF);
  u16* ATu = (u16*)(sm + L_ATT);
  u16* Pu  = (u16*)(sm + L_PT);

  // ---- P0 (once): stage CVI/CVE/SVC + embedding tables ----
  {
    const float4* src = (const float4*)(ws + CVI_F);
    float4* dst = (float4*)sm;
    for (int v = t; v < 109; v += 256) dst[v] = src[v];
    for (int i = t; i < 300; i += 256) {   // FIX: was `if (t < 300)` — lost 256..299
      const void* srcp; int off;
      if (i < 70)       { srcp = aqi_idE;      off = i;       }
      else if (i < 96)  { srcp = aqi_monthE;   off = i - 70;  }
      else if (i < 110) { srcp = aqi_weekdayE; off = i - 96;  }
      else if (i < 158) { srcp = aqi_hourE;    off = i - 110; }
      else if (i < 176) { srcp = meo_windE;    off = i - 158; }
      else if (i < 212) { srcp = meo_idE;      off = i - 176; }
      else if (i < 238) { srcp = meo_monthE;   off = i - 212; }
      else if (i < 252) { srcp = meo_weekdayE; off = i - 238; }
      else              { srcp = meo_hourE;    off = i - 252; }
      sm[L_ETA + i] = ldf(srcp, off, bf);
    }
  }
  // hoist batch-invariant Wt B-fragments into registers (L1/L2-hot global)
  const int lane = t & 63, w = t >> 6;
  const int mm = lane & 15, q4 = lane >> 4;
  const u16* wt = (const u16*)ws;
  s8v wb0 = ld_frag(wt + (mm)      * 32 + q4 * 8);
  s8v wb1 = ld_frag(wt + (16 + mm) * 32 + q4 * 8);
  s8v wb2 = ld_frag(wt + (32 + mm) * 32 + q4 * 8);
  s8v wb3 = ld_frag(wt + (48 + mm) * 32 + q4 * 8);
  __syncthreads();

  for (int e = 0; e < PERB; ++e) {
    const int b = blockIdx.x * PERB + e;
    if (b >= B) break;

    // ---- P1: Af (block-diag bf16), Ef via LDS tables, zero-fills ----
    for (int idx = t; idx < 654; idx += 256) {
      if (idx < 140) {                     // aqi inp -> Af[r][0..15]
        int r = idx >> 2, j = idx & 3;
        uint2 v;
        if (bf) v = ((const uint2*)aqi_inp)[((long)b * NAQ + r) * 4 + j];
        else {
          float4 f = ((const float4*)aqi_inp)[((long)b * NAQ + r) * 4 + j];
          v.x = ((u32)f2bf(f.y) << 16) | f2bf(f.x);
          v.y = ((u32)f2bf(f.w) << 16) | f2bf(f.z);
        }
        *(uint2*)(AFu + r * AF_STR + j * 4) = v;
      } else if (idx < 212) {              // meo inp -> Af[35+i][16..31]
        int z = idx - 140;
        int i = z >> 2, j = z & 3;
        uint2 v;
        if (bf) v = ((const uint2*)meo_inp)[((long)b * NME + i) * 4 + j];
        else {
          float4 f = ((const float4*)meo_inp)[((long)b * NME + i) * 4 + j];
          v.x = ((u32)f2bf(f.y) << 16) | f2bf(f.x);
          v.y = ((u32)f2bf(f.w) << 16) | f2bf(f.z);
        }
        *(uint2*)(AFu + (NAQ + i) * AF_STR + 16 + j * 4) = v;
      } else if (idx < 352) {              // zero Af[r][16..31]
        int z = idx - 212;
        int r = z >> 2, j = z & 3;
        *(uint2*)(AFu + r * AF_STR + 16 + j * 4) = make_uint2(0, 0);
      } else if (idx < 424) {              // zero Af[35+i][0..15]
        int z = idx - 352;
        int i = z >> 2, j = z & 3;
        *(uint2*)(AFu + (NAQ + i) * AF_STR + j * 4) = make_uint2(0, 0);
      } else if (idx < 564) {              // aqi embeddings via LDS tables
        int z = idx - 424;
        int r = z >> 2, p = z & 3;
        int ee = aqi_ex[((long)b * NAQ + r) * 4 + p];
        int base = L_ETA + ((p == 0) ? 0 : (p == 1) ? 70 : (p == 2) ? 96 : 110);
        sm[L_EFA + r * 9 + p * 2]     = sm[base + ee * 2];
        sm[L_EFA + r * 9 + p * 2 + 1] = sm[base + ee * 2 + 1];
      } else {                             // meo embeddings via LDS tables
        int z = idx - 564;
        int i = z / 5, p = z - i * 5;
        int ee = meo_ex[((long)b * NME + i) * 5 + p];
        int base = L_ETA + 158 + ((p == 0) ? 0 : (p == 1) ? 18 : (p == 2) ? 54
                                 : (p == 3) ? 80 : 94);
        sm[L_EFM + i * 11 + p * 2]     = sm[base + ee * 2];
        sm[L_EFM + i * 11 + p * 2 + 1] = sm[base + ee * 2 + 1];
      }
    }
    {   // zero ATt pad cols k=53..63
      int c = t & 63;
      for (int kk = t >> 6; kk < 11; kk += 4) ATu[c * P_STR + 53 + kk] = 0;
    }
    __syncthreads();

    // ---- P2: MFMA GEMM1 Af(64x32) @ Wt^T -> ATt ; P3: projections ----
    {
      s8v av = ld_frag(AFu + (16 * w + mm) * AF_STR + q4 * 8);
#pragma unroll
      for (int nt = 0; nt < 4; ++nt) {
        f4v acc = {0.f, 0.f, 0.f, 0.f};
        s8v bv = (nt == 0) ? wb0 : (nt == 1) ? wb1 : (nt == 2) ? wb2 : wb3;
        acc = __builtin_amdgcn_mfma_f32_16x16x32_bf16(av, bv, acc, 0, 0, 0);
        const int c = nt * 16 + mm;
#pragma unroll
        for (int reg = 0; reg < 4; ++reg) {
          const int r = 16 * w + q4 * 4 + reg;
          if (r < NN) ATu[c * P_STR + r] = f2bf(acc[reg]);
        }
      }
      if (t < 212) {   // P3: svw = SVC + dot(inp,CVi) + dot(emb,CVe)
        const int r = t >> 2, role = t & 3;
        const bool isA = (r < NAQ);
        const int tr = (isA ? 0 : 4) + role;
        const u16* arow = AFu + r * AF_STR + (isA ? 0 : 16);
        const float* Ci = sm + L_CVI + tr * 16;
        float s = 0.f;
#pragma unroll
        for (int k = 0; k < 16; ++k)
          s = fmaf(__uint_as_float(((u32)arow[k]) << 16), Ci[k], s);
        const int E = isA ? 8 : 10;
        const float* Ef = isA ? (sm + L_EFA + r * 9) : (sm + L_EFM + (r - NAQ) * 11);
        const float* Ce = sm + L_CVE + tr * 12;
        for (int k = 0; k < E; ++k) s = fmaf(Ef[k], Ce[k], s);
        sm[L_SVW + role * 53 + r] = sm[L_SVC + role * 53 + r] + s;
      }
    }
    __syncthreads();

    // ---- P4: softmax -> P bf16 (rinv-folded); P aliases dead Af/Ef ----
    {
      const int r = t >> 2, q = t & 3;
      const int j0 = q * 14;
      if (r < NN) {
        float ev[14];
        float m = -3.0e38f, ssum = 0.f;
        const float s1 = sm[L_SVW + r], s2 = sm[L_SVW + 53 + r];
        const float* tb = sm + L_SVW + ((r < NAQ) ? 106 : 159);
        const float* ebrow = ws + EBW_F + r * 56;   // L1/L2-hot
#pragma unroll
        for (int jj = 0; jj < 14; ++jj) {
          const int j = j0 + jj;
          float v = -3.0e38f;
          if (j < NN) {
            float eb = ebrow[j];
            float rr = ((j < NAQ) ? s1 : s2) + tb[j] + eb;
            v = (eb > 1e29f) ? -1.0e12f : ((rr > 0.f) ? rr : 0.2f * rr);
          }
          ev[jj] = v;
          m = fmaxf(m, v);
        }
        m = fmaxf(m, __shfl_xor(m, 1, 64));
        m = fmaxf(m, __shfl_xor(m, 2, 64));
#pragma unroll
        for (int jj = 0; jj < 14; ++jj) {
          float pv = ((j0 + jj) < NN) ? __expf(ev[jj] - m) : 0.f;
          ev[jj] = pv;
          ssum += pv;
        }
        ssum += __shfl_xor(ssum, 1, 64);
        ssum += __shfl_xor(ssum, 2, 64);
        const float rinv = 1.f / ssum;
#pragma unroll
        for (int jj = 0; jj < 14; ++jj) {
          const int j = j0 + jj;
          Pu[r * P_STR + j] = (j < NN) ? f2bf(ev[jj] * rinv) : (u16)0;
        }
        if (q == 0) *(uint4*)(Pu + r * P_STR + 56) = make_uint4(0, 0, 0, 0);
      } else {
        for (int idx = t - 212; idx < 99; idx += 44) {
          int row = 53 + idx / 9, o = idx - (idx / 9) * 9;
          *(uint4*)(Pu + row * P_STR + o * 8) = make_uint4(0, 0, 0, 0);
        }
      }
    }
    __syncthreads();

    // ---- P5: MFMA GEMM2 P @ AT -> stage (aliases P after frag loads) ----
    {
      const u16* Ar = Pu + (16 * w + mm) * P_STR + q4 * 8;
      s8v av0 = ld_frag(Ar);
      s8v av1 = ld_frag(Ar + 32);
      f4v acc[4];
#pragma unroll
      for (int nt = 0; nt < 4; ++nt) {
        const u16* Br = ATu + (16 * nt + mm) * P_STR + q4 * 8;
        s8v bv0 = ld_frag(Br);
        s8v bv1 = ld_frag(Br + 32);
        f4v a = {0.f, 0.f, 0.f, 0.f};
        a = __builtin_amdgcn_mfma_f32_16x16x32_bf16(av0, bv0, a, 0, 0, 0);
        a = __builtin_amdgcn_mfma_f32_16x16x32_bf16(av1, bv1, a, 0, 0, 0);
        acc[nt] = a;
      }
      __syncthreads();   // all waves' frag loads done; safe to clobber Pu
#pragma unroll
      for (int nt = 0; nt < 4; ++nt) {
        const int cgl = 16 * nt + mm;
#pragma unroll
        for (int reg = 0; reg < 4; ++reg) {
          const int rg = 16 * w + q4 * 4 + reg;
          if (rg < NN) Pu[rg * P_STR + cgl] = f2bf(acc[nt][reg]);
        }
      }
    }
    __syncthreads();

    // ---- P6: coalesced store 53 rows x 128B ----
    for (int idx = t; idx < 424; idx += 256) {
      int r = idx >> 3, o = idx & 7;
      long off = (r < NAQ)
        ? (long)b * (NAQ * FD) + (long)r * FD + o * 8
        : (long)B * (NAQ * FD) + (long)b * (NME * FD) + (long)(r - NAQ) * FD + o * 8;
      uint4 v = *(const uint4*)(Pu + r * P_STR + o * 8);
      if (bf) {
        *(uint4*)((u16*)out + off) = v;
      } else {
        float* po = (float*)out + off;
        po[0] = __uint_as_float(v.x << 16); po[1] = __uint_as_float(v.x & 0xFFFF0000u);
        po[2] = __uint_as_float(v.y << 16); po[3] = __uint_as_float(v.y & 0xFFFF0000u);
        po[4] = __uint_as_float(v.z << 16); po[5] = __uint_as_float(v.z & 0xFFFF0000u);
        po[6] = __uint_as_float(v.w << 16); po[7] = __uint_as_float(v.w & 0xFFFF0000u);
      }
    }
    __syncthreads();   // LDS reused by next element
  }
}

extern "C" void kernel_launch(void* const* d_in, const int* in_sizes, int n_in,
                              void* d_out, int out_size, void* d_ws, size_t ws_size,
                              hipStream_t stream)
{
  const void* aqi_inp      = d_in[0];
  const void* meo_inp      = d_in[1];
  const void* ctx          = d_in[2];
  const void* adjn         = d_in[3];
  const void* aqi_idE      = d_in[4];
  const void* aqi_monthE   = d_in[5];
  const void* aqi_weekdayE = d_in[6];
  const void* aqi_hourE    = d_in[7];
  const void* meo_windE    = d_in[8];
  const void* meo_idE      = d_in[9];
  const void* meo_monthE   = d_in[10];
  const void* meo_weekdayE = d_in[11];
  const void* meo_hourE    = d_in[12];
  const void* Wxa          = d_in[13];
  const void* Wxm          = d_in[14];
  const void* Wua          = d_in[15];
  const void* Wum          = d_in[16];
  const void* a_aa         = d_in[17];
  const void* a_am         = d_in[18];
  const void* a_ma         = d_in[19];
  const void* a_mm         = d_in[20];
  const int*  aqi_ex       = (const int*)d_in[21];
  const int*  meo_ex       = (const int*)d_in[22];
  const int*  adj          = (const int*)d_in[23];
  float* ws = (float*)d_ws;
  const int B = in_sizes[0] / (NAQ * 16);

  hipLaunchKernelGGL(prep_kernel, dim3((5452 + 255) / 256), dim3(256), 0, stream,
                     ctx, adjn, Wxa, Wxm, Wua, Wum, a_aa, a_am, a_ma, a_mm, adj, ws);
  hipLaunchKernelGGL(hga_main, dim3((B + PERB - 1) / PERB), dim3(256), 0, stream,
                     aqi_inp, meo_inp, ctx, aqi_idE, aqi_monthE, aqi_weekdayE, aqi_hourE,
                     meo_windE, meo_idE, meo_monthE, meo_weekdayE, meo_hourE,
                     aqi_ex, meo_ex, ws, d_out, B);
}

// Round 12
// 191.900 us; speedup vs baseline: 1.0746x; 1.0746x over previous
//
#include <hip/hip_runtime.h>
#include <hip/hip_bf16.h>

#define NAQ 35
#define NME 18
#define NN  53
#define FD  64
#define CTXD 60
#define PERB 2          // batch elements per block

// ---- ws layout ----
// u16 [0, 2048): Wt[64][32] bf16  (Wt[n][k] = k<16 ? Wxa[k][n] : Wxm[k-16][n])
#define CVI_F   1024    // float: 8*16 inp-part of folded C-vectors
#define CVE_F   1152    // float: 8*12 emb-part
#define SVC_F   1248    // float: 4*53 ctx-part of projections
#define EBW_F   1460    // float: 53*56 masked bias (1e30 sentinel)
#define WS_FLOATS 4428

// ---- LDS layout (float offsets; u16 regions 16B-aligned) ----
#define L_CVI   0       // 128
#define L_CVE   128     // 96
#define L_SVC   224     // 212
#define L_ETA   436     // 300: staged embedding tables (aqi 158 | meo 142)
#define L_AF    736     // u16[64][40] block-diag A bf16 (1280 f)
#define L_EFA   2016    // 35*9 fp32 emb (aqi)
#define L_EFM   2331    // 18*11 fp32 emb (meo)
#define L_PT    736     // u16[64][72]: P bf16 — ALIASES AF/EFA/EFM (dead); also out-stage
#define L_ATT   3040    // u16[64][72]: attri transposed bf16 (2304 f)
#define L_SVW   5344    // 212
#define S_TOTAL 5556    // 22,224 B
#define P_STR   72
#define AF_STR  40

typedef unsigned int   u32;
typedef unsigned short u16;
typedef short s8v __attribute__((ext_vector_type(8)));
typedef float f4v __attribute__((ext_vector_type(4)));

__device__ __forceinline__ float ldf(const void* p, long i, bool bf) {
  if (bf) { u16 h = ((const u16*)p)[i]; return __uint_as_float(((u32)h) << 16); }
  return ((const float*)p)[i];
}
__device__ __forceinline__ u16 f2bf(float f) {
  u32 u = __float_as_uint(f);
  return (u16)((u + 0x7FFFu + ((u >> 16) & 1u)) >> 16);
}
__device__ __forceinline__ bool sniff_bf16(const void* ctx) {
  const u32* w = (const u32*)ctx;
  bool ok = true;
#pragma unroll
  for (int k = 0; k < 32; ++k) {
    u32 e = (w[k] >> 7) & 0xFFu;
    ok = ok && (e >= 96u && e <= 160u);
  }
  return ok;
}
__device__ __forceinline__ s8v ld_frag(const u16* p) {
  union { float4 f; s8v s; } u;
  u.f = *(const float4*)(const void*)p;
  return u.s;
}

// =======================================================================
// prep: batch-invariant tables -> ws  (verified round 9)
// =======================================================================
__global__ void prep_kernel(
    const void* __restrict__ ctx, const void* __restrict__ adjn,
    const void* __restrict__ Wxa, const void* __restrict__ Wxm,
    const void* __restrict__ Wua, const void* __restrict__ Wum,
    const void* __restrict__ a_aa, const void* __restrict__ a_am,
    const void* __restrict__ a_ma, const void* __restrict__ a_mm,
    const int* __restrict__ adj, float* __restrict__ ws)
{
  const bool bf = sniff_bf16(ctx);
  int tid = blockIdx.x * blockDim.x + threadIdx.x;
  if (tid < 2048) {                        // Wt[n][k] bf16
    int n = tid >> 5, kk = tid & 31;
    float v = (kk < 16) ? ldf(Wxa, kk * 64 + n, bf)
                        : ldf(Wxm, (kk - 16) * 64 + n, bf);
    ((u16*)ws)[tid] = f2bf(v);
    return;
  }
  int fi = tid - 1024;                     // float index
  if (fi < CVE_F) {                        // CVi[tr][k], k<16
    int idx = fi - CVI_F;
    int tr = idx >> 4, k = idx & 15;
    const void* Wu = (tr < 4) ? Wua : Wum;
    const void* av; int off;
    switch (tr) {
      case 0: av = a_aa; off = 0;   break;
      case 1: av = a_am; off = 0;   break;
      case 2: av = a_aa; off = 124; break;
      case 3: av = a_ma; off = 124; break;
      case 4: av = a_ma; off = 0;   break;
      case 5: av = a_mm; off = 0;   break;
      case 6: av = a_am; off = 124; break;
      default: av = a_mm; off = 124; break;
    }
    float s = 0.f;
    for (int f = 0; f < 64; ++f) s += ldf(Wu, k * 64 + f, bf) * ldf(av, off + f, bf);
    ws[fi] = s;
  } else if (fi < SVC_F) {                 // CVe[tr][e]
    int idx = fi - CVE_F;
    int tr = idx / 12, e = idx - tr * 12;
    int E = (tr < 4) ? 8 : 10;
    float v = 0.f;
    if (e < E) {
      const void* Wu = (tr < 4) ? Wua : Wum;
      const void* av; int off;
      switch (tr) {
        case 0: av = a_aa; off = 0;   break;
        case 1: av = a_am; off = 0;   break;
        case 2: av = a_aa; off = 124; break;
        case 3: av = a_ma; off = 124; break;
        case 4: av = a_ma; off = 0;   break;
        case 5: av = a_mm; off = 0;   break;
        case 6: av = a_am; off = 124; break;
        default: av = a_mm; off = 124; break;
      }
      float s = 0.f;
      for (int f = 0; f < 64; ++f) s += ldf(Wu, (16 + e) * 64 + f, bf) * ldf(av, off + f, bf);
      v = s;
    }
    ws[fi] = v;
  } else if (fi < EBW_F) {                 // SVC
    int idx = fi - SVC_F;
    int arr = idx / 53, i = idx - arr * 53;
    int isA = (i < NAQ);
    const void* av; int off;
    if (arr == 0)      { av = isA ? a_aa : a_ma; off = 64;  }
    else if (arr == 1) { av = isA ? a_am : a_mm; off = 64;  }
    else if (arr == 2) { av = isA ? a_aa : a_am; off = 188; }
    else               { av = isA ? a_ma : a_mm; off = 188; }
    float s = 0.f;
    for (int c = 0; c < CTXD; ++c) s += ldf(ctx, i * CTXD + c, bf) * ldf(av, off + c, bf);
    ws[fi] = s;
  } else if (fi < WS_FLOATS) {             // EB masked bias
    int idx = fi - EBW_F;
    int i = idx / 56, j = idx - i * 56;
    float v = 1e30f;
    if (j < NN && adj[i * NN + j] > 0) {
      const void* aq = (i < NAQ) ? ((j < NAQ) ? a_aa : a_am)
                                 : ((j < NAQ) ? a_ma : a_mm);
      v = ldf(adjn, i * NN + j, bf) * ldf(aq, 248, bf);
    }
    ws[fi] = v;
  }
}

// =======================================================================
// main: one block = PERB batch elements; both GEMMs on MFMA
// =======================================================================
__global__ __launch_bounds__(256, 6) void hga_main(
    const void* __restrict__ aqi_inp, const void* __restrict__ meo_inp,
    const void* __restrict__ ctx,
    const void* __restrict__ aqi_idE, const void* __restrict__ aqi_monthE,
    const void* __restrict__ aqi_weekdayE, const void* __restrict__ aqi_hourE,
    const void* __restrict__ meo_windE, const void* __restrict__ meo_idE,
    const void* __restrict__ meo_monthE, const void* __restrict__ meo_weekdayE,
    const void* __restrict__ meo_hourE,
    const int* __restrict__ aqi_ex, const int* __restrict__ meo_ex,
    const float* __restrict__ ws, void* __restrict__ out, int B)
{
  __shared__ __align__(16) float sm[S_TOTAL];
  const int t = threadIdx.x;
  const bool bf = sniff_bf16(ctx);
  u16* AFu = (u16*)(sm + L_AF);
  u16* ATu = (u16*)(sm + L_ATT);
  u16* Pu  = (u16*)(sm + L_PT);

  // ---- P0 (once): stage CVI/CVE/SVC + embedding tables ----
  {
    const float4* src = (const float4*)(ws + CVI_F);
    float4* dst = (float4*)sm;
    for (int v = t; v < 109; v += 256) dst[v] = src[v];
    for (int i = t; i < 300; i += 256) {
      const void* srcp; int off;
      if (i < 70)       { srcp = aqi_idE;      off = i;       }
      else if (i < 96)  { srcp = aqi_monthE;   off = i - 70;  }
      else if (i < 110) { srcp = aqi_weekdayE; off = i - 96;  }
      else if (i < 158) { srcp = aqi_hourE;    off = i - 110; }
      else if (i < 176) { srcp = meo_windE;    off = i - 158; }
      else if (i < 212) { srcp = meo_idE;      off = i - 176; }
      else if (i < 238) { srcp = meo_monthE;   off = i - 212; }
      else if (i < 252) { srcp = meo_weekdayE; off = i - 238; }
      else              { srcp = meo_hourE;    off = i - 252; }
      sm[L_ETA + i] = ldf(srcp, off, bf);
    }
  }
  const int lane = t & 63, w = t >> 6;
  const int mm = lane & 15, q4 = lane >> 4;
  __syncthreads();

  for (int e = 0; e < PERB; ++e) {
    const int b = blockIdx.x * PERB + e;
    if (b >= B) break;

    // ---- P1: Af (block-diag bf16), Ef via LDS tables, zero-fills ----
    for (int idx = t; idx < 654; idx += 256) {
      if (idx < 140) {                     // aqi inp -> Af[r][0..15]
        int r = idx >> 2, j = idx & 3;
        uint2 v;
        if (bf) v = ((const uint2*)aqi_inp)[((long)b * NAQ + r) * 4 + j];
        else {
          float4 f = ((const float4*)aqi_inp)[((long)b * NAQ + r) * 4 + j];
          v.x = ((u32)f2bf(f.y) << 16) | f2bf(f.x);
          v.y = ((u32)f2bf(f.w) << 16) | f2bf(f.z);
        }
        *(uint2*)(AFu + r * AF_STR + j * 4) = v;
      } else if (idx < 212) {              // meo inp -> Af[35+i][16..31]
        int z = idx - 140;
        int i = z >> 2, j = z & 3;
        uint2 v;
        if (bf) v = ((const uint2*)meo_inp)[((long)b * NME + i) * 4 + j];
        else {
          float4 f = ((const float4*)meo_inp)[((long)b * NME + i) * 4 + j];
          v.x = ((u32)f2bf(f.y) << 16) | f2bf(f.x);
          v.y = ((u32)f2bf(f.w) << 16) | f2bf(f.z);
        }
        *(uint2*)(AFu + (NAQ + i) * AF_STR + 16 + j * 4) = v;
      } else if (idx < 352) {              // zero Af[r][16..31]
        int z = idx - 212;
        int r = z >> 2, j = z & 3;
        *(uint2*)(AFu + r * AF_STR + 16 + j * 4) = make_uint2(0, 0);
      } else if (idx < 424) {              // zero Af[35+i][0..15]
        int z = idx - 352;
        int i = z >> 2, j = z & 3;
        *(uint2*)(AFu + (NAQ + i) * AF_STR + j * 4) = make_uint2(0, 0);
      } else if (idx < 564) {              // aqi embeddings via LDS tables
        int z = idx - 424;
        int r = z >> 2, p = z & 3;
        int ee = aqi_ex[((long)b * NAQ + r) * 4 + p];
        int base = L_ETA + ((p == 0) ? 0 : (p == 1) ? 70 : (p == 2) ? 96 : 110);
        sm[L_EFA + r * 9 + p * 2]     = sm[base + ee * 2];
        sm[L_EFA + r * 9 + p * 2 + 1] = sm[base + ee * 2 + 1];
      } else {                             // meo embeddings via LDS tables
        int z = idx - 564;
        int i = z / 5, p = z - i * 5;
        int ee = meo_ex[((long)b * NME + i) * 5 + p];
        int base = L_ETA + 158 + ((p == 0) ? 0 : (p == 1) ? 18 : (p == 2) ? 54
                                 : (p == 3) ? 80 : 94);
        sm[L_EFM + i * 11 + p * 2]     = sm[base + ee * 2];
        sm[L_EFM + i * 11 + p * 2 + 1] = sm[base + ee * 2 + 1];
      }
    }
    {   // zero ATt pad cols k=53..63
      int c = t & 63;
      for (int kk = t >> 6; kk < 11; kk += 4) ATu[c * P_STR + 53 + kk] = 0;
    }
    __syncthreads();

    // ---- P2: MFMA GEMM1 Af(64x32) @ Wt^T -> ATt ; P3: projections ----
    {
      const u16* wt = (const u16*)ws;     // L1-hot; loaded per element (no hoist)
      s8v av = ld_frag(AFu + (16 * w + mm) * AF_STR + q4 * 8);
#pragma unroll
      for (int nt = 0; nt < 4; ++nt) {
        f4v acc = {0.f, 0.f, 0.f, 0.f};
        s8v bv = ld_frag(wt + (16 * nt + mm) * 32 + q4 * 8);
        acc = __builtin_amdgcn_mfma_f32_16x16x32_bf16(av, bv, acc, 0, 0, 0);
        const int c = nt * 16 + mm;
#pragma unroll
        for (int reg = 0; reg < 4; ++reg) {
          const int r = 16 * w + q4 * 4 + reg;
          if (r < NN) ATu[c * P_STR + r] = f2bf(acc[reg]);
        }
      }
      if (t < 212) {   // P3: svw = SVC + dot(inp,CVi) + dot(emb,CVe)
        const int r = t >> 2, role = t & 3;
        const bool isA = (r < NAQ);
        const int tr = (isA ? 0 : 4) + role;
        const u16* arow = AFu + r * AF_STR + (isA ? 0 : 16);
        const float* Ci = sm + L_CVI + tr * 16;
        float s = 0.f;
#pragma unroll
        for (int k = 0; k < 16; ++k)
          s = fmaf(__uint_as_float(((u32)arow[k]) << 16), Ci[k], s);
        const int E = isA ? 8 : 10;
        const float* Ef = isA ? (sm + L_EFA + r * 9) : (sm + L_EFM + (r - NAQ) * 11);
        const float* Ce = sm + L_CVE + tr * 12;
        for (int k = 0; k < E; ++k) s = fmaf(Ef[k], Ce[k], s);
        sm[L_SVW + role * 53 + r] = sm[L_SVC + role * 53 + r] + s;
      }
    }
    __syncthreads();

    // ---- P4: softmax -> P bf16 (rinv-folded); P aliases dead Af/Ef ----
    {
      const int r = t >> 2, q = t & 3;
      const int j0 = q * 14;
      if (r < NN) {
        float ev[14];
        float m = -3.0e38f, ssum = 0.f;
        const float s1 = sm[L_SVW + r], s2 = sm[L_SVW + 53 + r];
        const float* tb = sm + L_SVW + ((r < NAQ) ? 106 : 159);
        const float* ebrow = ws + EBW_F + r * 56;   // L1/L2-hot
#pragma unroll
        for (int jj = 0; jj < 14; ++jj) {
          const int j = j0 + jj;
          float v = -3.0e38f;
          if (j < NN) {
            float eb = ebrow[j];
            float rr = ((j < NAQ) ? s1 : s2) + tb[j] + eb;
            v = (eb > 1e29f) ? -1.0e12f : ((rr > 0.f) ? rr : 0.2f * rr);
          }
          ev[jj] = v;
          m = fmaxf(m, v);
        }
        m = fmaxf(m, __shfl_xor(m, 1, 64));
        m = fmaxf(m, __shfl_xor(m, 2, 64));
#pragma unroll
        for (int jj = 0; jj < 14; ++jj) {
          float pv = ((j0 + jj) < NN) ? __expf(ev[jj] - m) : 0.f;
          ev[jj] = pv;
          ssum += pv;
        }
        ssum += __shfl_xor(ssum, 1, 64);
        ssum += __shfl_xor(ssum, 2, 64);
        const float rinv = 1.f / ssum;
#pragma unroll
        for (int jj = 0; jj < 14; ++jj) {
          const int j = j0 + jj;
          Pu[r * P_STR + j] = (j < NN) ? f2bf(ev[jj] * rinv) : (u16)0;
        }
        if (q == 0) *(uint4*)(Pu + r * P_STR + 56) = make_uint4(0, 0, 0, 0);
      } else {
        for (int idx = t - 212; idx < 99; idx += 44) {
          int row = 53 + idx / 9, o = idx - (idx / 9) * 9;
          *(uint4*)(Pu + row * P_STR + o * 8) = make_uint4(0, 0, 0, 0);
        }
      }
    }
    __syncthreads();

    // ---- P5: MFMA GEMM2 P @ AT -> stage (aliases P after frag loads) ----
    {
      const u16* Ar = Pu + (16 * w + mm) * P_STR + q4 * 8;
      s8v av0 = ld_frag(Ar);
      s8v av1 = ld_frag(Ar + 32);
      f4v acc[4];
#pragma unroll
      for (int nt = 0; nt < 4; ++nt) {
        const u16* Br = ATu + (16 * nt + mm) * P_STR + q4 * 8;
        s8v bv0 = ld_frag(Br);
        s8v bv1 = ld_frag(Br + 32);
        f4v a = {0.f, 0.f, 0.f, 0.f};
        a = __builtin_amdgcn_mfma_f32_16x16x32_bf16(av0, bv0, a, 0, 0, 0);
        a = __builtin_amdgcn_mfma_f32_16x16x32_bf16(av1, bv1, a, 0, 0, 0);
        acc[nt] = a;
      }
      __syncthreads();   // all waves' frag loads done; safe to clobber Pu
#pragma unroll
      for (int nt = 0; nt < 4; ++nt) {
        const int cgl = 16 * nt + mm;
#pragma unroll
        for (int reg = 0; reg < 4; ++reg) {
          const int rg = 16 * w + q4 * 4 + reg;
          if (rg < NN) Pu[rg * P_STR + cgl] = f2bf(acc[nt][reg]);
        }
      }
    }
    __syncthreads();

    // ---- P6: coalesced store 53 rows x 128B ----
    for (int idx = t; idx < 424; idx += 256) {
      int r = idx >> 3, o = idx & 7;
      long off = (r < NAQ)
        ? (long)b * (NAQ * FD) + (long)r * FD + o * 8
        : (long)B * (NAQ * FD) + (long)b * (NME * FD) + (long)(r - NAQ) * FD + o * 8;
      uint4 v = *(const uint4*)(Pu + r * P_STR + o * 8);
      if (bf) {
        *(uint4*)((u16*)out + off) = v;
      } else {
        float* po = (float*)out + off;
        po[0] = __uint_as_float(v.x << 16); po[1] = __uint_as_float(v.x & 0xFFFF0000u);
        po[2] = __uint_as_float(v.y << 16); po[3] = __uint_as_float(v.y & 0xFFFF0000u);
        po[4] = __uint_as_float(v.z << 16); po[5] = __uint_as_float(v.z & 0xFFFF0000u);
        po[6] = __uint_as_float(v.w << 16); po[7] = __uint_as_float(v.w & 0xFFFF0000u);
      }
    }
    __syncthreads();   // LDS reused by next element
  }
}

extern "C" void kernel_launch(void* const* d_in, const int* in_sizes, int n_in,
                              void* d_out, int out_size, void* d_ws, size_t ws_size,
                              hipStream_t stream)
{
  const void* aqi_inp      = d_in[0];
  const void* meo_inp      = d_in[1];
  const void* ctx          = d_in[2];
  const void* adjn         = d_in[3];
  const void* aqi_idE      = d_in[4];
  const void* aqi_monthE   = d_in[5];
  const void* aqi_weekdayE = d_in[6];
  const void* aqi_hourE    = d_in[7];
  const void* meo_windE    = d_in[8];
  const void* meo_idE      = d_in[9];
  const void* meo_monthE   = d_in[10];
  const void* meo_weekdayE = d_in[11];
  const void* meo_hourE    = d_in[12];
  const void* Wxa          = d_in[13];
  const void* Wxm          = d_in[14];
  const void* Wua          = d_in[15];
  const void* Wum          = d_in[16];
  const void* a_aa         = d_in[17];
  const void* a_am         = d_in[18];
  const void* a_ma         = d_in[19];
  const void* a_mm         = d_in[20];
  const int*  aqi_ex       = (const int*)d_in[21];
  const int*  meo_ex       = (const int*)d_in[22];
  const int*  adj          = (const int*)d_in[23];
  float* ws = (float*)d_ws;
  const int B = in_sizes[0] / (NAQ * 16);

  hipLaunchKernelGGL(prep_kernel, dim3((5452 + 255) / 256), dim3(256), 0, stream,
                     ctx, adjn, Wxa, Wxm, Wua, Wum, a_aa, a_am, a_ma, a_mm, adj, ws);
  hipLaunchKernelGGL(hga_main, dim3((B + PERB - 1) / PERB), dim3(256), 0, stream,
                     aqi_inp, meo_inp, ctx, aqi_idE, aqi_monthE, aqi_weekdayE, aqi_hourE,
                     meo_windE, meo_idE, meo_monthE, meo_weekdayE, meo_hourE,
                     aqi_ex, meo_ex, ws, d_out, B);
}